// Round 1
// baseline (430.760 us; speedup 1.0000x reference)
//
#include <hip/hip_runtime.h>

#define N_NODES 100000
#define N_EDGES 1600000
#define F_INPUT 256
#define H_DIM   128
#define C_DIM   40
#define NB1     ((N_NODES + 255) / 256)   // 391 scan blocks
#define NGEMM1  1563                      // 64-row tiles covering 100032 rows
#define NCOUNT  1563                      // 1024-edge chunks (4 edges/thread)
#define NMEGA   (NGEMM1 + NCOUNT)         // 3126
#define PSTR    32                        // packed counter stride in u32 (128B/line)

typedef short  bf8   __attribute__((ext_vector_type(8)));
typedef float  f32x4 __attribute__((ext_vector_type(4)));
typedef float  f32x2 __attribute__((ext_vector_type(2)));
typedef unsigned short u16x8 __attribute__((ext_vector_type(8)));

static __device__ __forceinline__ unsigned short f2bf(float f) {
    union { float f; unsigned u; } v; v.f = f;
    unsigned r = v.u + 0x7FFFu + ((v.u >> 16) & 1u);
    return (unsigned short)(r >> 16);
}
static __device__ __forceinline__ float bf2f(unsigned short b) {
    union { unsigned u; float f; } v; v.u = ((unsigned)b) << 16;
    return v.f;
}
static __device__ __forceinline__ f32x2 bfpair(unsigned u) {
    union { unsigned u; float f; } lo, hi;
    lo.u = u << 16; hi.u = u & 0xFFFF0000u;
    return (f32x2){lo.f, hi.f};
}

// ---------- k_pre: init packed  ∪  pack W1/W2 into MFMA B-frag layout ----------
__global__ void k_pre(unsigned* packed, const float* __restrict__ W1,
                      const float* __restrict__ W2,
                      unsigned short* Wp1, unsigned short* Wp2) {
    if (blockIdx.x < NB1) {
        int i = blockIdx.x * 256 + threadIdx.x;
        if (i < N_NODES) packed[(size_t)i * PSTR] = (1u << 16);  // deg=1.0 (self loop), Q16
        return;
    }
    int idx = (blockIdx.x - NB1) * 256 + threadIdx.x;
    if (idx < 32768) {       // 8 nt * 8 ks * 64 * 8
        int j = idx & 7, lane = (idx >> 3) & 63, ks = (idx >> 9) & 7, nt = idx >> 12;
        int m = lane & 15, q = lane >> 4;
        Wp1[idx] = f2bf(W1[(ks * 32 + q * 8 + j) * H_DIM + nt * 16 + m]);
    }
    int idx2 = idx - 32768;  // 3 nt * 4 ks * 64 * 8 = 6144
    if (idx2 >= 0 && idx2 < 6144) {
        int j = idx2 & 7, lane = (idx2 >> 3) & 63, ks = (idx2 >> 9) & 3, nt = idx2 >> 11;
        int m = lane & 15, q = lane >> 4;
        int n = nt * 16 + m;
        Wp2[idx2] = (n < C_DIM) ? f2bf(W2[(ks * 32 + q * 8 + j) * C_DIM + n]) : (unsigned short)0;
    }
}

// ---------- k_mega: GEMM1 (h = x@W1, bf16, unscaled)  ∪  edge count/degree ----------
// Independent chains co-scheduled. Count role: 4 edges/thread, 4 independent
// atomics in flight; counters padded to 1/128B line to kill cross-XCD
// same-line ownership ping-pong. Interleave gemm:count 1:1.
__global__ __launch_bounds__(256, 4) void k_mega(
        const float* __restrict__ x, const unsigned short* __restrict__ Wp,
        unsigned short* __restrict__ h,
        const int* __restrict__ col, const float* __restrict__ ea,
        unsigned* packed, int* __restrict__ rank) {
    __shared__ unsigned short lds_out[64 * H_DIM];
    int b = blockIdx.x;
    bool is_gemm = ((b & 1) == 0);
    if (!is_gemm) {
        // ---- count role: 1024 edges per block, 4 per thread ----
        int cb = b >> 1;                            // 0..1562
        int e0 = cb * 1024 + threadIdx.x;
        int cs[4]; unsigned qs[4]; unsigned old[4];
#pragma unroll
        for (int k = 0; k < 4; k++) {
            int e = e0 + k * 256;
            if (e < N_EDGES) {
                cs[k] = col[e];
                qs[k] = __float2uint_rn(ea[e] * 65536.0f);   // Q16
            } else cs[k] = -1;
        }
#pragma unroll
        for (int k = 0; k < 4; k++)
            if (cs[k] >= 0)
                old[k] = atomicAdd(packed + (size_t)cs[k] * PSTR, (1u << 24) | qs[k]);
#pragma unroll
        for (int k = 0; k < 4; k++) {
            int e = e0 + k * 256;
            if (e < N_EDGES) rank[e] = (int)(old[k] >> 24);
        }
        return;
    }
    // ---- gemm role: 64 rows per block ----
    int tile = b >> 1;                              // 0..1562
    int tid = threadIdx.x;
    int wave = tid >> 6, lane = tid & 63;
    int m = lane & 15, q = lane >> 4;
    int row0 = tile * 64 + wave * 16;
    int rowA = row0 + m; if (rowA >= N_NODES) rowA = N_NODES - 1;

    f32x4 acc[8];
#pragma unroll
    for (int i = 0; i < 8; i++) acc[i] = (f32x4){0.f, 0.f, 0.f, 0.f};
    const float* xr = x + (long)rowA * F_INPUT + q * 8;
#pragma unroll
    for (int ks = 0; ks < 8; ks++) {
        float4 a0 = *(const float4*)(xr + ks * 32);
        float4 a1 = *(const float4*)(xr + ks * 32 + 4);
        bf8 a;
        a[0] = (short)f2bf(a0.x); a[1] = (short)f2bf(a0.y);
        a[2] = (short)f2bf(a0.z); a[3] = (short)f2bf(a0.w);
        a[4] = (short)f2bf(a1.x); a[5] = (short)f2bf(a1.y);
        a[6] = (short)f2bf(a1.z); a[7] = (short)f2bf(a1.w);
#pragma unroll
        for (int nt = 0; nt < 8; nt++) {
            bf8 bb = *(const bf8*)(Wp + (((nt * 8 + ks) * 64 + lane) << 3));
            acc[nt] = __builtin_amdgcn_mfma_f32_16x16x32_bf16(a, bb, acc[nt], 0, 0, 0);
        }
    }
    int lrow = wave * 16 + q * 4;
#pragma unroll
    for (int nt = 0; nt < 8; nt++)
#pragma unroll
        for (int r = 0; r < 4; r++)
            lds_out[(lrow + r) * H_DIM + nt * 16 + m] = f2bf(acc[nt][r]);
    __syncthreads();
    int valid = N_NODES - tile * 64; if (valid > 64) valid = 64;
    unsigned short* gbase = h + (size_t)tile * 64 * H_DIM;
#pragma unroll
    for (int i = 0; i < 4; i++) {
        int idx = (i * 256 + tid) * 8;
        if (idx < valid * H_DIM)
            *(u16x8*)(gbase + idx) = *(const u16x8*)(lds_out + idx);
    }
}

// ---------- scan + dinv + compact count ----------
__global__ void k_scan1(const unsigned* __restrict__ packed, int* start, int* bsum,
                        float* dinv, int* __restrict__ cnt) {
    __shared__ int s[256];
    int i = blockIdx.x * 256 + threadIdx.x;
    unsigned pk = (i < N_NODES) ? packed[(size_t)i * PSTR] : 0;
    if (i < N_NODES) {
        dinv[i] = rsqrtf((float)(pk & 0xFFFFFFu) * (1.0f / 65536.0f));
        cnt[i] = (int)(pk >> 24);
    }
    int v = (int)(pk >> 24);
    s[threadIdx.x] = v; __syncthreads();
    for (int off = 1; off < 256; off <<= 1) {
        int t = (threadIdx.x >= off) ? s[threadIdx.x - off] : 0;
        __syncthreads();
        s[threadIdx.x] += t;
        __syncthreads();
    }
    if (i < N_NODES) start[i] = s[threadIdx.x] - v;
    if (threadIdx.x == 255) bsum[blockIdx.x] = s[255];
}

__global__ void k_scan2(int* bsum) {
    __shared__ int s[512];
    int v = (threadIdx.x < NB1) ? bsum[threadIdx.x] : 0;
    s[threadIdx.x] = v; __syncthreads();
    for (int off = 1; off < 512; off <<= 1) {
        int t = (threadIdx.x >= off) ? s[threadIdx.x - off] : 0;
        __syncthreads();
        s[threadIdx.x] += t;
        __syncthreads();
    }
    if (threadIdx.x < NB1) bsum[threadIdx.x] = s[threadIdx.x] - v;
}

// atomic-free scatter; csr weight = ea * dinv[row]  (dest-side dinv applied in agg)
__global__ void k_scatter(const int* __restrict__ row, const int* __restrict__ col,
                          const float* __restrict__ ea, const float* __restrict__ dinv,
                          const int* __restrict__ start, const int* __restrict__ bsum,
                          const int* __restrict__ rank, int2* __restrict__ csr) {
    int e = blockIdx.x * 256 + threadIdx.x;
    if (e < N_EDGES) {
        int c = col[e];
        int r = row[e];
        int pos = start[c] + bsum[c >> 8] + rank[e];
        float w = ea[e] * dinv[r];
        csr[pos] = make_int2(r, __float_as_int(w));
    }
}

// ---------- aggregation layer 1: wave/node, predicated 20-slot gather ----------
// h1[c] = relu(di*(di*h[c] + sum w_e*h[row_e]) + b1),  w_e = ea*dinv[row]
__global__ void k_agg1(const unsigned short* __restrict__ h, const int2* __restrict__ csr,
                       const int* __restrict__ start, const int* __restrict__ bsum,
                       const int* __restrict__ cnt,
                       const float* __restrict__ dinv, const float* __restrict__ b1,
                       unsigned short* __restrict__ h1) {
    int c = (blockIdx.x * blockDim.x + threadIdx.x) >> 6;
    int lane = threadIdx.x & 63;
    if (c >= N_NODES) return;
    int eg = lane >> 4, cl = lane & 15;
    float di = dinv[c];
    int s = start[c] + bsum[c >> 8];
    int n = cnt[c];

    float w[5]; int r[5];
#pragma unroll
    for (int t = 0; t < 5; t++) {
        int i = eg + 4 * t;
        int2 p = csr[s + ((i < n) ? i : 0)];
        bool val = (i < n);
        r[t] = val ? p.x : c;
        w[t] = val ? __int_as_float(p.y) : 0.f;
    }
    uint4 gv[5];
#pragma unroll
    for (int t = 0; t < 5; t++)
        gv[t] = *(const uint4*)(h + (long)r[t] * H_DIM + cl * 8);
    uint4 selfv = (eg == 0) ? *(const uint4*)(h + (long)c * H_DIM + cl * 8)
                            : (uint4){0, 0, 0, 0};

    f32x2 acc[4];
#pragma unroll
    for (int k = 0; k < 4; k++) acc[k] = (f32x2){0.f, 0.f};
    {
        unsigned sv[4] = {selfv.x, selfv.y, selfv.z, selfv.w};
        f32x2 dd = (f32x2){di, di};
        if (eg == 0)
#pragma unroll
            for (int k = 0; k < 4; k++) acc[k] += dd * bfpair(sv[k]);
    }
#pragma unroll
    for (int t = 0; t < 5; t++) {
        unsigned vv[4] = {gv[t].x, gv[t].y, gv[t].z, gv[t].w};
        f32x2 ww = (f32x2){w[t], w[t]};
#pragma unroll
        for (int k = 0; k < 4; k++) acc[k] += ww * bfpair(vv[k]);
    }
    for (int i = 20 + eg; i < n; i += 4) {
        int2 p = csr[s + i];
        uint4 v4 = *(const uint4*)(h + (long)p.x * H_DIM + cl * 8);
        unsigned vv[4] = {v4.x, v4.y, v4.z, v4.w};
        float wt = __int_as_float(p.y);
        f32x2 ww = (f32x2){wt, wt};
#pragma unroll
        for (int k = 0; k < 4; k++) acc[k] += ww * bfpair(vv[k]);
    }
#pragma unroll
    for (int k = 0; k < 4; k++) {
        acc[k].x += __shfl_xor(acc[k].x, 16); acc[k].y += __shfl_xor(acc[k].y, 16);
        acc[k].x += __shfl_xor(acc[k].x, 32); acc[k].y += __shfl_xor(acc[k].y, 32);
    }
    if (eg == 0) {
        u16x8 o;
#pragma unroll
        for (int k = 0; k < 4; k++) {
            o[2 * k]     = f2bf(fmaxf(di * acc[k].x + b1[cl * 8 + 2 * k], 0.f));
            o[2 * k + 1] = f2bf(fmaxf(di * acc[k].y + b1[cl * 8 + 2 * k + 1], 0.f));
        }
        *(u16x8*)(h1 + (long)c * H_DIM + cl * 8) = o;
    }
}

// ---------- GEMM2: h2(bf16) = h1 @ W2 (unscaled), LDS store-transpose ----------
__global__ __launch_bounds__(256, 4) void k_gemm2(const unsigned short* __restrict__ h1,
                        const unsigned short* __restrict__ Wp,
                        unsigned short* __restrict__ h2) {
    __shared__ unsigned short lds_out[64 * C_DIM];
    int tid = threadIdx.x;
    int wave = tid >> 6, lane = tid & 63;
    int m = lane & 15, q = lane >> 4;
    int row0 = blockIdx.x * 64 + wave * 16;
    int rowA = row0 + m; if (rowA >= N_NODES) rowA = N_NODES - 1;

    f32x4 acc[3];
#pragma unroll
    for (int i = 0; i < 3; i++) acc[i] = (f32x4){0.f, 0.f, 0.f, 0.f};
    const unsigned short* hr = h1 + (long)rowA * H_DIM + q * 8;
#pragma unroll
    for (int ks = 0; ks < 4; ks++) {
        bf8 a = *(const bf8*)(hr + ks * 32);
#pragma unroll
        for (int nt = 0; nt < 3; nt++) {
            bf8 b = *(const bf8*)(Wp + (((nt * 4 + ks) * 64 + lane) << 3));
            acc[nt] = __builtin_amdgcn_mfma_f32_16x16x32_bf16(a, b, acc[nt], 0, 0, 0);
        }
    }
    int lrow = wave * 16 + q * 4;
#pragma unroll
    for (int nt = 0; nt < 3; nt++)
#pragma unroll
        for (int r = 0; r < 4; r++) {
            int colo = nt * 16 + m;
            if (colo < C_DIM)
                lds_out[(lrow + r) * C_DIM + colo] = f2bf(acc[nt][r]);
        }
    __syncthreads();
    int valid = N_NODES - blockIdx.x * 64; if (valid > 64) valid = 64;
    unsigned short* gbase = h2 + (size_t)blockIdx.x * 64 * C_DIM;
    int total = valid * C_DIM;
#pragma unroll
    for (int i = 0; i < 3; i++) {
        int idx = (i * 256 + tid) * 4;
        if (idx < total)
            *(uint2*)(gbase + idx) = *(const uint2*)(lds_out + idx);
    }
}

// ---------- aggregation layer 2 + bias + log_softmax: predicated 24-slot gather ----------
__global__ void k_agg2(const unsigned short* __restrict__ h2, const int2* __restrict__ csr,
                       const int* __restrict__ start, const int* __restrict__ bsum,
                       const int* __restrict__ cnt,
                       const float* __restrict__ dinv, const float* __restrict__ b2,
                       float* __restrict__ out) {
    int c = (blockIdx.x * blockDim.x + threadIdx.x) >> 6;
    int lane = threadIdx.x & 63;
    if (c >= N_NODES) return;
    int eg = lane >> 3, cl = lane & 7;
    float di = dinv[c];
    int s = start[c] + bsum[c >> 8];
    int n = cnt[c];

    float w[3]; int r[3];
#pragma unroll
    for (int t = 0; t < 3; t++) {
        int i = eg + 8 * t;
        int2 p = csr[s + ((i < n) ? i : 0)];
        bool val = (i < n);
        r[t] = val ? p.x : c;
        w[t] = val ? __int_as_float(p.y) : 0.f;
    }
    uint4 gv[3] = {{0,0,0,0},{0,0,0,0},{0,0,0,0}};
    uint4 selfv = {0, 0, 0, 0};
    if (cl < 5) {
#pragma unroll
        for (int t = 0; t < 3; t++)
            gv[t] = *(const uint4*)(h2 + (long)r[t] * C_DIM + cl * 8);
        if (eg == 0) selfv = *(const uint4*)(h2 + (long)c * C_DIM + cl * 8);
    }
    f32x2 acc[4];
#pragma unroll
    for (int k = 0; k < 4; k++) acc[k] = (f32x2){0.f, 0.f};
    {
        unsigned sv[4] = {selfv.x, selfv.y, selfv.z, selfv.w};
        f32x2 dd = (f32x2){di, di};
        if (eg == 0 && cl < 5)
#pragma unroll
            for (int k = 0; k < 4; k++) acc[k] += dd * bfpair(sv[k]);
    }
#pragma unroll
    for (int t = 0; t < 3; t++) {
        unsigned vv[4] = {gv[t].x, gv[t].y, gv[t].z, gv[t].w};
        f32x2 ww = (f32x2){w[t], w[t]};
#pragma unroll
        for (int k = 0; k < 4; k++) acc[k] += ww * bfpair(vv[k]);
    }
    for (int i = 24 + eg; i < n; i += 8) {
        int2 p = csr[s + i];
        if (cl < 5) {
            uint4 v4 = *(const uint4*)(h2 + (long)p.x * C_DIM + cl * 8);
            unsigned vv[4] = {v4.x, v4.y, v4.z, v4.w};
            float wt = __int_as_float(p.y);
            f32x2 ww = (f32x2){wt, wt};
#pragma unroll
            for (int k = 0; k < 4; k++) acc[k] += ww * bfpair(vv[k]);
        }
    }
#pragma unroll
    for (int k = 0; k < 4; k++) {
        acc[k].x += __shfl_xor(acc[k].x, 8);  acc[k].y += __shfl_xor(acc[k].y, 8);
        acc[k].x += __shfl_xor(acc[k].x, 16); acc[k].y += __shfl_xor(acc[k].y, 16);
        acc[k].x += __shfl_xor(acc[k].x, 32); acc[k].y += __shfl_xor(acc[k].y, 32);
    }
    float v[8];
    float lm = -INFINITY;
    if (cl < 5) {
#pragma unroll
        for (int k = 0; k < 4; k++) {
            v[2 * k]     = di * acc[k].x + b2[cl * 8 + 2 * k];
            v[2 * k + 1] = di * acc[k].y + b2[cl * 8 + 2 * k + 1];
            lm = fmaxf(lm, fmaxf(v[2 * k], v[2 * k + 1]));
        }
    }
    lm = fmaxf(lm, __shfl_xor(lm, 1));
    lm = fmaxf(lm, __shfl_xor(lm, 2));
    lm = fmaxf(lm, __shfl_xor(lm, 4));
    float ls = 0.f;
    if (cl < 5) {
#pragma unroll
        for (int j = 0; j < 8; j++) ls += __expf(v[j] - lm);
    }
    ls += __shfl_xor(ls, 1);
    ls += __shfl_xor(ls, 2);
    ls += __shfl_xor(ls, 4);
    if (eg == 0 && cl < 5) {
        float lsm = lm + logf(ls);
        f32x4 o0, o1;
#pragma unroll
        for (int j = 0; j < 4; j++) { o0[j] = v[j] - lsm; o1[j] = v[j + 4] - lsm; }
        *(f32x4*)(out + (long)c * C_DIM + cl * 8)     = o0;
        *(f32x4*)(out + (long)c * C_DIM + cl * 8 + 4) = o1;
    }
}

extern "C" void kernel_launch(void* const* d_in, const int* in_sizes, int n_in,
                              void* d_out, int out_size, void* d_ws, size_t ws_size,
                              hipStream_t stream) {
    const float* x  = (const float*)d_in[0];
    const int*   ei = (const int*)d_in[1];
    const float* ea = (const float*)d_in[2];
    const float* W1 = (const float*)d_in[3];
    const float* b1 = (const float*)d_in[4];
    const float* W2 = (const float*)d_in[5];
    const float* b2 = (const float*)d_in[6];
    const int* row = ei;
    const int* col = ei + N_EDGES;

    char* ws = (char*)d_ws;
    size_t off = 0;
    auto alloc = [&](size_t bytes) -> void* {
        void* p = ws + off;
        off = (off + bytes + 255) & ~(size_t)255;
        return p;
    };
    unsigned*       packed = (unsigned*)alloc((size_t)N_NODES * PSTR * 4);
    float*          dinv   = (float*)alloc((size_t)N_NODES * 4);
    int*            rank   = (int*)alloc((size_t)N_EDGES * 4);
    int*            start  = (int*)alloc((size_t)N_NODES * 4);
    int*            bsum   = (int*)alloc(512 * 4);
    int*            cnt    = (int*)alloc((size_t)N_NODES * 4);
    int2*           csr    = (int2*)alloc((size_t)N_EDGES * 8);   // NOT last: OOB-safe slot reads
    unsigned short* Wp1    = (unsigned short*)alloc(32768 * 2);
    unsigned short* Wp2    = (unsigned short*)alloc(6144 * 2);
    unsigned short* h      = (unsigned short*)alloc((size_t)(N_NODES + 64) * H_DIM * 2);
    unsigned short* h1     = (unsigned short*)alloc((size_t)N_NODES * H_DIM * 2);
    unsigned short* h2     = (unsigned short*)alloc((size_t)(N_NODES + 64) * C_DIM * 2);

    k_pre<<<NB1 + 152, 256, 0, stream>>>(packed, W1, W2, Wp1, Wp2);
    k_mega<<<NMEGA, 256, 0, stream>>>(x, Wp1, h, col, ea, packed, rank);
    k_scan1<<<NB1, 256, 0, stream>>>(packed, start, bsum, dinv, cnt);
    k_scan2<<<1, 512, 0, stream>>>(bsum);
    k_scatter<<<N_EDGES / 256, 256, 0, stream>>>(row, col, ea, dinv, start, bsum, rank, csr);
    k_agg1<<<N_NODES / 4, 256, 0, stream>>>(h, csr, start, bsum, cnt, dinv, b1, h1);
    k_gemm2<<<(N_NODES + 63) / 64, 256, 0, stream>>>(h1, Wp2, h2);
    k_agg2<<<N_NODES / 4, 256, 0, stream>>>(h2, csr, start, bsum, cnt, dinv, b2, (float*)d_out);
}

// Round 2
// 412.914 us; speedup vs baseline: 1.0432x; 1.0432x over previous
//
#include <hip/hip_runtime.h>

#define N_NODES 100000
#define N_EDGES 1600000
#define F_INPUT 256
#define H_DIM   128
#define C_DIM   40
#define NB1     ((N_NODES + 255) / 256)   // 391 scan blocks
#define NB8     ((8 * N_NODES + 255) / 256) // 3125 init blocks for packed8
#define NGEMM1  1563                      // 64-row tiles covering 100032 rows
#define NCOUNT  6250                      // 256-edge chunks
#define NMEGA   (NGEMM1 + NCOUNT)         // 7813

typedef short  bf8   __attribute__((ext_vector_type(8)));
typedef float  f32x4 __attribute__((ext_vector_type(4)));
typedef float  f32x2 __attribute__((ext_vector_type(2)));
typedef unsigned short u16x8 __attribute__((ext_vector_type(8)));

static __device__ __forceinline__ unsigned short f2bf(float f) {
    union { float f; unsigned u; } v; v.f = f;
    unsigned r = v.u + 0x7FFFu + ((v.u >> 16) & 1u);
    return (unsigned short)(r >> 16);
}
static __device__ __forceinline__ float bf2f(unsigned short b) {
    union { unsigned u; float f; } v; v.u = ((unsigned)b) << 16;
    return v.f;
}
static __device__ __forceinline__ f32x2 bfpair(unsigned u) {
    union { unsigned u; float f; } lo, hi;
    lo.u = u << 16; hi.u = u & 0xFFFF0000u;
    return (f32x2){lo.f, hi.f};
}
static __device__ __forceinline__ unsigned xcc_id() {
    unsigned x;
    asm volatile("s_getreg_b32 %0, hwreg(HW_REG_XCC_ID)" : "=s"(x));
    return x & 7u;
}

// ---------- k_pre: init packed8 (8 XCD-private copies)  ∪  pack W1/W2 ----------
__global__ void k_pre(unsigned* packed8, const float* __restrict__ W1,
                      const float* __restrict__ W2,
                      unsigned short* Wp1, unsigned short* Wp2) {
    if (blockIdx.x < NB8) {
        int i = blockIdx.x * 256 + threadIdx.x;
        // copy 0 (nodes 0..N-1) carries the self-loop weight 1.0 in Q16; copies 1..7 start 0
        if (i < 8 * N_NODES) packed8[i] = (i < N_NODES) ? (1u << 16) : 0u;
        return;
    }
    int idx = (blockIdx.x - NB8) * 256 + threadIdx.x;
    if (idx < 32768) {       // 8 nt * 8 ks * 64 * 8
        int j = idx & 7, lane = (idx >> 3) & 63, ks = (idx >> 9) & 7, nt = idx >> 12;
        int m = lane & 15, q = lane >> 4;
        Wp1[idx] = f2bf(W1[(ks * 32 + q * 8 + j) * H_DIM + nt * 16 + m]);
    }
    int idx2 = idx - 32768;  // 3 nt * 4 ks * 64 * 8 = 6144
    if (idx2 >= 0 && idx2 < 6144) {
        int j = idx2 & 7, lane = (idx2 >> 3) & 63, ks = (idx2 >> 9) & 3, nt = idx2 >> 11;
        int m = lane & 15, q = lane >> 4;
        int n = nt * 16 + m;
        Wp2[idx2] = (n < C_DIM) ? f2bf(W2[(ks * 32 + q * 8 + j) * C_DIM + n]) : (unsigned short)0;
    }
}

// ---------- k_mega: GEMM1 (h = x@W1, bf16, unscaled)  ∪  edge count/degree ----------
// Count role uses XCD-private counters + workgroup-scope (L2-local) fetch-add:
// avoids the memory-side per-op HBM RMW of device-scope atomicAdd. rank packs
// (xcd<<8)|rank-within-xcd. Interleave gemm:count 1:4 via blockIdx%5 (round-0 proven).
__global__ __launch_bounds__(256, 4) void k_mega(
        const float* __restrict__ x, const unsigned short* __restrict__ Wp,
        unsigned short* __restrict__ h,
        const int* __restrict__ col, const float* __restrict__ ea,
        unsigned* packed8, int* __restrict__ rank) {
    __shared__ unsigned short lds_out[64 * H_DIM];
    int b = blockIdx.x;
    bool is_gemm = (b % 5 == 0);
    if (!is_gemm) {
        // ---- count role ----
        int cb = b - b / 5 - 1;                     // 0..6249
        int e = cb * 256 + threadIdx.x;
        if (e < N_EDGES) {
            int c = col[e];
            unsigned q = __float2uint_rn(ea[e] * 65536.0f);   // Q16
            unsigned xcd = xcc_id();
            unsigned old = __hip_atomic_fetch_add(
                packed8 + (size_t)xcd * N_NODES + c, (1u << 24) | q,
                __ATOMIC_RELAXED, __HIP_MEMORY_SCOPE_WORKGROUP);
            rank[e] = (int)((old >> 24) | (xcd << 8));
        }
        return;
    }
    // ---- gemm role: 64 rows per block ----
    int tile = b / 5;                               // 0..1562
    int tid = threadIdx.x;
    int wave = tid >> 6, lane = tid & 63;
    int m = lane & 15, q = lane >> 4;
    int row0 = tile * 64 + wave * 16;
    int rowA = row0 + m; if (rowA >= N_NODES) rowA = N_NODES - 1;

    f32x4 acc[8];
#pragma unroll
    for (int i = 0; i < 8; i++) acc[i] = (f32x4){0.f, 0.f, 0.f, 0.f};
    const float* xr = x + (long)rowA * F_INPUT + q * 8;
#pragma unroll
    for (int ks = 0; ks < 8; ks++) {
        float4 a0 = *(const float4*)(xr + ks * 32);
        float4 a1 = *(const float4*)(xr + ks * 32 + 4);
        bf8 a;
        a[0] = (short)f2bf(a0.x); a[1] = (short)f2bf(a0.y);
        a[2] = (short)f2bf(a0.z); a[3] = (short)f2bf(a0.w);
        a[4] = (short)f2bf(a1.x); a[5] = (short)f2bf(a1.y);
        a[6] = (short)f2bf(a1.z); a[7] = (short)f2bf(a1.w);
#pragma unroll
        for (int nt = 0; nt < 8; nt++) {
            bf8 bb = *(const bf8*)(Wp + (((nt * 8 + ks) * 64 + lane) << 3));
            acc[nt] = __builtin_amdgcn_mfma_f32_16x16x32_bf16(a, bb, acc[nt], 0, 0, 0);
        }
    }
    int lrow = wave * 16 + q * 4;
#pragma unroll
    for (int nt = 0; nt < 8; nt++)
#pragma unroll
        for (int r = 0; r < 4; r++)
            lds_out[(lrow + r) * H_DIM + nt * 16 + m] = f2bf(acc[nt][r]);
    __syncthreads();
    int valid = N_NODES - tile * 64; if (valid > 64) valid = 64;
    unsigned short* gbase = h + (size_t)tile * 64 * H_DIM;
#pragma unroll
    for (int i = 0; i < 4; i++) {
        int idx = (i * 256 + tid) * 8;
        if (idx < valid * H_DIM)
            *(u16x8*)(gbase + idx) = *(const u16x8*)(lds_out + idx);
    }
}

// ---------- scan + dinv + compact count + per-XCD exclusive offsets ----------
__global__ void k_scan1(const unsigned* __restrict__ packed8, int* start, int* bsum,
                        float* dinv, int* __restrict__ cnt, uint2* __restrict__ xoff) {
    __shared__ int s[256];
    int i = blockIdx.x * 256 + threadIdx.x;
    int v = 0;
    if (i < N_NODES) {
        unsigned wsum = 0, run = 0;
        unsigned lo = 0, hi = 0;
#pragma unroll
        for (int xc = 0; xc < 8; xc++) {
            unsigned pk = packed8[(size_t)xc * N_NODES + i];
            unsigned c = pk >> 24;
            wsum += pk & 0xFFFFFFu;
            if (xc < 4) lo |= (run & 0xFFu) << (8 * xc);
            else        hi |= (run & 0xFFu) << (8 * (xc - 4));
            run += c;
        }
        dinv[i] = rsqrtf((float)wsum * (1.0f / 65536.0f));
        cnt[i] = (int)run;
        xoff[i] = make_uint2(lo, hi);
        v = (int)run;
    }
    s[threadIdx.x] = v; __syncthreads();
    for (int off = 1; off < 256; off <<= 1) {
        int t = (threadIdx.x >= off) ? s[threadIdx.x - off] : 0;
        __syncthreads();
        s[threadIdx.x] += t;
        __syncthreads();
    }
    if (i < N_NODES) start[i] = s[threadIdx.x] - v;
    if (threadIdx.x == 255) bsum[blockIdx.x] = s[255];
}

__global__ void k_scan2(int* bsum) {
    __shared__ int s[512];
    int v = (threadIdx.x < NB1) ? bsum[threadIdx.x] : 0;
    s[threadIdx.x] = v; __syncthreads();
    for (int off = 1; off < 512; off <<= 1) {
        int t = (threadIdx.x >= off) ? s[threadIdx.x - off] : 0;
        __syncthreads();
        s[threadIdx.x] += t;
        __syncthreads();
    }
    if (threadIdx.x < NB1) bsum[threadIdx.x] = s[threadIdx.x] - v;
}

// atomic-free scatter; csr weight = ea * dinv[row]  (dest-side dinv applied in agg)
__global__ void k_scatter(const int* __restrict__ row, const int* __restrict__ col,
                          const float* __restrict__ ea, const float* __restrict__ dinv,
                          const int* __restrict__ start, const int* __restrict__ bsum,
                          const int* __restrict__ rank, const uint2* __restrict__ xoff,
                          int2* __restrict__ csr) {
    int e = blockIdx.x * 256 + threadIdx.x;
    if (e < N_EDGES) {
        int c = col[e];
        int r = row[e];
        int rk = rank[e];
        int xcd = rk >> 8, r0 = rk & 0xFF;
        uint2 xo = xoff[c];
        unsigned w32 = (xcd & 4) ? xo.y : xo.x;
        int off = (int)((w32 >> (8 * (xcd & 3))) & 0xFFu);
        int pos = start[c] + bsum[c >> 8] + off + r0;
        float w = ea[e] * dinv[r];
        csr[pos] = make_int2(r, __float_as_int(w));
    }
}

// ---------- aggregation layer 1: wave/node, predicated 20-slot gather ----------
// h1[c] = relu(di*(di*h[c] + sum w_e*h[row_e]) + b1),  w_e = ea*dinv[row]
__global__ void k_agg1(const unsigned short* __restrict__ h, const int2* __restrict__ csr,
                       const int* __restrict__ start, const int* __restrict__ bsum,
                       const int* __restrict__ cnt,
                       const float* __restrict__ dinv, const float* __restrict__ b1,
                       unsigned short* __restrict__ h1) {
    int c = (blockIdx.x * blockDim.x + threadIdx.x) >> 6;
    int lane = threadIdx.x & 63;
    if (c >= N_NODES) return;
    int eg = lane >> 4, cl = lane & 15;
    float di = dinv[c];
    int s = start[c] + bsum[c >> 8];
    int n = cnt[c];

    float w[5]; int r[5];
#pragma unroll
    for (int t = 0; t < 5; t++) {
        int i = eg + 4 * t;
        int2 p = csr[s + ((i < n) ? i : 0)];
        bool val = (i < n);
        r[t] = val ? p.x : c;
        w[t] = val ? __int_as_float(p.y) : 0.f;
    }
    uint4 gv[5];
#pragma unroll
    for (int t = 0; t < 5; t++)
        gv[t] = *(const uint4*)(h + (long)r[t] * H_DIM + cl * 8);
    uint4 selfv = (eg == 0) ? *(const uint4*)(h + (long)c * H_DIM + cl * 8)
                            : (uint4){0, 0, 0, 0};

    f32x2 acc[4];
#pragma unroll
    for (int k = 0; k < 4; k++) acc[k] = (f32x2){0.f, 0.f};
    {
        unsigned sv[4] = {selfv.x, selfv.y, selfv.z, selfv.w};
        f32x2 dd = (f32x2){di, di};
        if (eg == 0)
#pragma unroll
            for (int k = 0; k < 4; k++) acc[k] += dd * bfpair(sv[k]);
    }
#pragma unroll
    for (int t = 0; t < 5; t++) {
        unsigned vv[4] = {gv[t].x, gv[t].y, gv[t].z, gv[t].w};
        f32x2 ww = (f32x2){w[t], w[t]};
#pragma unroll
        for (int k = 0; k < 4; k++) acc[k] += ww * bfpair(vv[k]);
    }
    for (int i = 20 + eg; i < n; i += 4) {
        int2 p = csr[s + i];
        uint4 v4 = *(const uint4*)(h + (long)p.x * H_DIM + cl * 8);
        unsigned vv[4] = {v4.x, v4.y, v4.z, v4.w};
        float wt = __int_as_float(p.y);
        f32x2 ww = (f32x2){wt, wt};
#pragma unroll
        for (int k = 0; k < 4; k++) acc[k] += ww * bfpair(vv[k]);
    }
#pragma unroll
    for (int k = 0; k < 4; k++) {
        acc[k].x += __shfl_xor(acc[k].x, 16); acc[k].y += __shfl_xor(acc[k].y, 16);
        acc[k].x += __shfl_xor(acc[k].x, 32); acc[k].y += __shfl_xor(acc[k].y, 32);
    }
    if (eg == 0) {
        u16x8 o;
#pragma unroll
        for (int k = 0; k < 4; k++) {
            o[2 * k]     = f2bf(fmaxf(di * acc[k].x + b1[cl * 8 + 2 * k], 0.f));
            o[2 * k + 1] = f2bf(fmaxf(di * acc[k].y + b1[cl * 8 + 2 * k + 1], 0.f));
        }
        *(u16x8*)(h1 + (long)c * H_DIM + cl * 8) = o;
    }
}

// ---------- GEMM2: h2(bf16) = h1 @ W2 (unscaled), LDS store-transpose ----------
__global__ __launch_bounds__(256, 4) void k_gemm2(const unsigned short* __restrict__ h1,
                        const unsigned short* __restrict__ Wp,
                        unsigned short* __restrict__ h2) {
    __shared__ unsigned short lds_out[64 * C_DIM];
    int tid = threadIdx.x;
    int wave = tid >> 6, lane = tid & 63;
    int m = lane & 15, q = lane >> 4;
    int row0 = blockIdx.x * 64 + wave * 16;
    int rowA = row0 + m; if (rowA >= N_NODES) rowA = N_NODES - 1;

    f32x4 acc[3];
#pragma unroll
    for (int i = 0; i < 3; i++) acc[i] = (f32x4){0.f, 0.f, 0.f, 0.f};
    const unsigned short* hr = h1 + (long)rowA * H_DIM + q * 8;
#pragma unroll
    for (int ks = 0; ks < 4; ks++) {
        bf8 a = *(const bf8*)(hr + ks * 32);
#pragma unroll
        for (int nt = 0; nt < 3; nt++) {
            bf8 b = *(const bf8*)(Wp + (((nt * 4 + ks) * 64 + lane) << 3));
            acc[nt] = __builtin_amdgcn_mfma_f32_16x16x32_bf16(a, b, acc[nt], 0, 0, 0);
        }
    }
    int lrow = wave * 16 + q * 4;
#pragma unroll
    for (int nt = 0; nt < 3; nt++)
#pragma unroll
        for (int r = 0; r < 4; r++) {
            int colo = nt * 16 + m;
            if (colo < C_DIM)
                lds_out[(lrow + r) * C_DIM + colo] = f2bf(acc[nt][r]);
        }
    __syncthreads();
    int valid = N_NODES - blockIdx.x * 64; if (valid > 64) valid = 64;
    unsigned short* gbase = h2 + (size_t)blockIdx.x * 64 * C_DIM;
    int total = valid * C_DIM;
#pragma unroll
    for (int i = 0; i < 3; i++) {
        int idx = (i * 256 + tid) * 4;
        if (idx < total)
            *(uint2*)(gbase + idx) = *(const uint2*)(lds_out + idx);
    }
}

// ---------- aggregation layer 2 + bias + log_softmax: predicated 24-slot gather ----------
__global__ void k_agg2(const unsigned short* __restrict__ h2, const int2* __restrict__ csr,
                       const int* __restrict__ start, const int* __restrict__ bsum,
                       const int* __restrict__ cnt,
                       const float* __restrict__ dinv, const float* __restrict__ b2,
                       float* __restrict__ out) {
    int c = (blockIdx.x * blockDim.x + threadIdx.x) >> 6;
    int lane = threadIdx.x & 63;
    if (c >= N_NODES) return;
    int eg = lane >> 3, cl = lane & 7;
    float di = dinv[c];
    int s = start[c] + bsum[c >> 8];
    int n = cnt[c];

    float w[3]; int r[3];
#pragma unroll
    for (int t = 0; t < 3; t++) {
        int i = eg + 8 * t;
        int2 p = csr[s + ((i < n) ? i : 0)];
        bool val = (i < n);
        r[t] = val ? p.x : c;
        w[t] = val ? __int_as_float(p.y) : 0.f;
    }
    uint4 gv[3] = {{0,0,0,0},{0,0,0,0},{0,0,0,0}};
    uint4 selfv = {0, 0, 0, 0};
    if (cl < 5) {
#pragma unroll
        for (int t = 0; t < 3; t++)
            gv[t] = *(const uint4*)(h2 + (long)r[t] * C_DIM + cl * 8);
        if (eg == 0) selfv = *(const uint4*)(h2 + (long)c * C_DIM + cl * 8);
    }
    f32x2 acc[4];
#pragma unroll
    for (int k = 0; k < 4; k++) acc[k] = (f32x2){0.f, 0.f};
    {
        unsigned sv[4] = {selfv.x, selfv.y, selfv.z, selfv.w};
        f32x2 dd = (f32x2){di, di};
        if (eg == 0 && cl < 5)
#pragma unroll
            for (int k = 0; k < 4; k++) acc[k] += dd * bfpair(sv[k]);
    }
#pragma unroll
    for (int t = 0; t < 3; t++) {
        unsigned vv[4] = {gv[t].x, gv[t].y, gv[t].z, gv[t].w};
        f32x2 ww = (f32x2){w[t], w[t]};
#pragma unroll
        for (int k = 0; k < 4; k++) acc[k] += ww * bfpair(vv[k]);
    }
    for (int i = 24 + eg; i < n; i += 8) {
        int2 p = csr[s + i];
        if (cl < 5) {
            uint4 v4 = *(const uint4*)(h2 + (long)p.x * C_DIM + cl * 8);
            unsigned vv[4] = {v4.x, v4.y, v4.z, v4.w};
            float wt = __int_as_float(p.y);
            f32x2 ww = (f32x2){wt, wt};
#pragma unroll
            for (int k = 0; k < 4; k++) acc[k] += ww * bfpair(vv[k]);
        }
    }
#pragma unroll
    for (int k = 0; k < 4; k++) {
        acc[k].x += __shfl_xor(acc[k].x, 8);  acc[k].y += __shfl_xor(acc[k].y, 8);
        acc[k].x += __shfl_xor(acc[k].x, 16); acc[k].y += __shfl_xor(acc[k].y, 16);
        acc[k].x += __shfl_xor(acc[k].x, 32); acc[k].y += __shfl_xor(acc[k].y, 32);
    }
    float v[8];
    float lm = -INFINITY;
    if (cl < 5) {
#pragma unroll
        for (int k = 0; k < 4; k++) {
            v[2 * k]     = di * acc[k].x + b2[cl * 8 + 2 * k];
            v[2 * k + 1] = di * acc[k].y + b2[cl * 8 + 2 * k + 1];
            lm = fmaxf(lm, fmaxf(v[2 * k], v[2 * k + 1]));
        }
    }
    lm = fmaxf(lm, __shfl_xor(lm, 1));
    lm = fmaxf(lm, __shfl_xor(lm, 2));
    lm = fmaxf(lm, __shfl_xor(lm, 4));
    float ls = 0.f;
    if (cl < 5) {
#pragma unroll
        for (int j = 0; j < 8; j++) ls += __expf(v[j] - lm);
    }
    ls += __shfl_xor(ls, 1);
    ls += __shfl_xor(ls, 2);
    ls += __shfl_xor(ls, 4);
    if (eg == 0 && cl < 5) {
        float lsm = lm + logf(ls);
        f32x4 o0, o1;
#pragma unroll
        for (int j = 0; j < 4; j++) { o0[j] = v[j] - lsm; o1[j] = v[j + 4] - lsm; }
        *(f32x4*)(out + (long)c * C_DIM + cl * 8)     = o0;
        *(f32x4*)(out + (long)c * C_DIM + cl * 8 + 4) = o1;
    }
}

extern "C" void kernel_launch(void* const* d_in, const int* in_sizes, int n_in,
                              void* d_out, int out_size, void* d_ws, size_t ws_size,
                              hipStream_t stream) {
    const float* x  = (const float*)d_in[0];
    const int*   ei = (const int*)d_in[1];
    const float* ea = (const float*)d_in[2];
    const float* W1 = (const float*)d_in[3];
    const float* b1 = (const float*)d_in[4];
    const float* W2 = (const float*)d_in[5];
    const float* b2 = (const float*)d_in[6];
    const int* row = ei;
    const int* col = ei + N_EDGES;

    char* ws = (char*)d_ws;
    size_t off = 0;
    auto alloc = [&](size_t bytes) -> void* {
        void* p = ws + off;
        off = (off + bytes + 255) & ~(size_t)255;
        return p;
    };
    unsigned*       packed8 = (unsigned*)alloc((size_t)8 * N_NODES * 4);  // [xcd][node]
    float*          dinv    = (float*)alloc((size_t)N_NODES * 4);
    int*            rank    = (int*)alloc((size_t)N_EDGES * 4);
    int*            start   = (int*)alloc((size_t)N_NODES * 4);
    int*            bsum    = (int*)alloc(512 * 4);
    int*            cnt     = (int*)alloc((size_t)N_NODES * 4);
    uint2*          xoff    = (uint2*)alloc((size_t)N_NODES * 8);
    int2*           csr     = (int2*)alloc((size_t)N_EDGES * 8);   // NOT last: OOB-safe slot reads
    unsigned short* Wp1     = (unsigned short*)alloc(32768 * 2);
    unsigned short* Wp2     = (unsigned short*)alloc(6144 * 2);
    unsigned short* h       = (unsigned short*)alloc((size_t)(N_NODES + 64) * H_DIM * 2);
    unsigned short* h1      = (unsigned short*)alloc((size_t)N_NODES * H_DIM * 2);
    unsigned short* h2      = (unsigned short*)alloc((size_t)(N_NODES + 64) * C_DIM * 2);

    k_pre<<<NB8 + 152, 256, 0, stream>>>(packed8, W1, W2, Wp1, Wp2);
    k_mega<<<NMEGA, 256, 0, stream>>>(x, Wp1, h, col, ea, packed8, rank);
    k_scan1<<<NB1, 256, 0, stream>>>(packed8, start, bsum, dinv, cnt, xoff);
    k_scan2<<<1, 512, 0, stream>>>(bsum);
    k_scatter<<<N_EDGES / 256, 256, 0, stream>>>(row, col, ea, dinv, start, bsum, rank, xoff, csr);
    k_agg1<<<N_NODES / 4, 256, 0, stream>>>(h, csr, start, bsum, cnt, dinv, b1, h1);
    k_gemm2<<<(N_NODES + 63) / 64, 256, 0, stream>>>(h1, Wp2, h2);
    k_agg2<<<N_NODES / 4, 256, 0, stream>>>(h2, csr, start, bsum, cnt, dinv, b2, (float*)d_out);
}

// Round 3
// 408.260 us; speedup vs baseline: 1.0551x; 1.0114x over previous
//
#include <hip/hip_runtime.h>

#define N_NODES 100000
#define N_EDGES 1600000
#define F_INPUT 256
#define H_DIM   128
#define C_DIM   40
#define NBKT    391                       // node buckets of 256: 391*256 = 100096
#define NCHK    1563                      // 1024-edge chunks: 1563*1024 = 1600512
#define NMEGA   (2 * NCHK)                // gemm tiles ∪ hist chunks, 1:1

typedef short  bf8   __attribute__((ext_vector_type(8)));
typedef float  f32x4 __attribute__((ext_vector_type(4)));
typedef float  f32x2 __attribute__((ext_vector_type(2)));
typedef unsigned short u16x8 __attribute__((ext_vector_type(8)));

static __device__ __forceinline__ unsigned short f2bf(float f) {
    union { float f; unsigned u; } v; v.f = f;
    unsigned r = v.u + 0x7FFFu + ((v.u >> 16) & 1u);
    return (unsigned short)(r >> 16);
}
static __device__ __forceinline__ f32x2 bfpair(unsigned u) {
    union { unsigned u; float f; } lo, hi;
    lo.u = u << 16; hi.u = u & 0xFFFF0000u;
    return (f32x2){lo.f, hi.f};
}

// ---------- k_pre: pack W1/W2 into MFMA B-frag layout ----------
__global__ void k_pre(const float* __restrict__ W1, const float* __restrict__ W2,
                      unsigned short* Wp1, unsigned short* Wp2) {
    int idx = blockIdx.x * 256 + threadIdx.x;
    if (idx < 32768) {       // 8 nt * 8 ks * 64 * 8
        int j = idx & 7, lane = (idx >> 3) & 63, ks = (idx >> 9) & 7, nt = idx >> 12;
        int m = lane & 15, q = lane >> 4;
        Wp1[idx] = f2bf(W1[(ks * 32 + q * 8 + j) * H_DIM + nt * 16 + m]);
    }
    int idx2 = idx - 32768;  // 3 nt * 4 ks * 64 * 8 = 6144
    if (idx2 >= 0 && idx2 < 6144) {
        int j = idx2 & 7, lane = (idx2 >> 3) & 63, ks = (idx2 >> 9) & 3, nt = idx2 >> 11;
        int m = lane & 15, q = lane >> 4;
        int n = nt * 16 + m;
        Wp2[idx2] = (n < C_DIM) ? f2bf(W2[(ks * 32 + q * 8 + j) * C_DIM + n]) : (unsigned short)0;
    }
}

// ---------- k_mega2: GEMM1 (h = x@W1, bf16)  ∪  bucket histogram (LDS only) ----------
__global__ __launch_bounds__(256, 4) void k_mega2(
        const float* __restrict__ x, const unsigned short* __restrict__ Wp,
        unsigned short* __restrict__ h,
        const int* __restrict__ col, unsigned* __restrict__ histG) {
    __shared__ unsigned short lds_out[64 * H_DIM];   // 16 KB (hist role reuses prefix)
    int b = blockIdx.x;
    int tid = threadIdx.x;
    if (b & 1) {
        // ---- hist role: 1024 edges, LDS histogram over 391 buckets ----
        unsigned* histL = (unsigned*)lds_out;
        int chunk = b >> 1;                          // 0..1562
        for (int i = tid; i < NBKT; i += 256) histL[i] = 0;
        __syncthreads();
        int e0 = chunk * 1024 + tid;
#pragma unroll
        for (int k = 0; k < 4; k++) {
            int e = e0 + k * 256;
            if (e < N_EDGES) atomicAdd(&histL[col[e] >> 8], 1u);
        }
        __syncthreads();
        for (int i = tid; i < NBKT; i += 256) histG[(size_t)i * NCHK + chunk] = histL[i];
        return;
    }
    // ---- gemm role: 64 rows per block ----
    int tile = b >> 1;                               // 0..1562
    int wave = tid >> 6, lane = tid & 63;
    int m = lane & 15, q = lane >> 4;
    int row0 = tile * 64 + wave * 16;
    int rowA = row0 + m; if (rowA >= N_NODES) rowA = N_NODES - 1;

    f32x4 acc[8];
#pragma unroll
    for (int i = 0; i < 8; i++) acc[i] = (f32x4){0.f, 0.f, 0.f, 0.f};
    const float* xr = x + (long)rowA * F_INPUT + q * 8;
#pragma unroll
    for (int ks = 0; ks < 8; ks++) {
        float4 a0 = *(const float4*)(xr + ks * 32);
        float4 a1 = *(const float4*)(xr + ks * 32 + 4);
        bf8 a;
        a[0] = (short)f2bf(a0.x); a[1] = (short)f2bf(a0.y);
        a[2] = (short)f2bf(a0.z); a[3] = (short)f2bf(a0.w);
        a[4] = (short)f2bf(a1.x); a[5] = (short)f2bf(a1.y);
        a[6] = (short)f2bf(a1.z); a[7] = (short)f2bf(a1.w);
#pragma unroll
        for (int nt = 0; nt < 8; nt++) {
            bf8 bb = *(const bf8*)(Wp + (((nt * 8 + ks) * 64 + lane) << 3));
            acc[nt] = __builtin_amdgcn_mfma_f32_16x16x32_bf16(a, bb, acc[nt], 0, 0, 0);
        }
    }
    int lrow = wave * 16 + q * 4;
#pragma unroll
    for (int nt = 0; nt < 8; nt++)
#pragma unroll
        for (int r = 0; r < 4; r++)
            lds_out[(lrow + r) * H_DIM + nt * 16 + m] = f2bf(acc[nt][r]);
    __syncthreads();
    int valid = N_NODES - tile * 64; if (valid > 64) valid = 64;
    unsigned short* gbase = h + (size_t)tile * 64 * H_DIM;
#pragma unroll
    for (int i = 0; i < 4; i++) {
        int idx = (i * 256 + tid) * 8;
        if (idx < valid * H_DIM)
            *(u16x8*)(gbase + idx) = *(const u16x8*)(lds_out + idx);
    }
}

// ---------- scanB: per-bucket exclusive scan over its 1563 chunk counts ----------
__global__ void k_scanB(unsigned* histG, unsigned* bktTotal) {
    __shared__ unsigned s[256];
    int B = blockIdx.x, t = threadIdx.x;
    unsigned carry = 0;
    for (int c0 = 0; c0 < NCHK; c0 += 256) {
        int idx = c0 + t;
        unsigned v = (idx < NCHK) ? histG[(size_t)B * NCHK + idx] : 0;
        s[t] = v; __syncthreads();
        for (int off = 1; off < 256; off <<= 1) {
            unsigned u = (t >= off) ? s[t - off] : 0;
            __syncthreads();
            s[t] += u;
            __syncthreads();
        }
        if (idx < NCHK) histG[(size_t)B * NCHK + idx] = s[t] - v + carry;
        unsigned tot = s[255];
        __syncthreads();
        carry += tot;
    }
    if (t == 0) bktTotal[B] = carry;
}

// ---------- scanC: exclusive scan of 391 bucket totals -> bucketBase[392] ----------
__global__ void k_scanC(const unsigned* __restrict__ bktTotal, unsigned* bucketBase) {
    __shared__ unsigned s[256];
    int t = threadIdx.x;
    unsigned carry = 0;
    for (int c0 = 0; c0 < NBKT; c0 += 256) {
        int idx = c0 + t;
        unsigned v = (idx < NBKT) ? bktTotal[idx] : 0;
        s[t] = v; __syncthreads();
        for (int off = 1; off < 256; off <<= 1) {
            unsigned u = (t >= off) ? s[t - off] : 0;
            __syncthreads();
            s[t] += u;
            __syncthreads();
        }
        if (idx < NBKT) bucketBase[idx] = s[t] - v + carry;
        unsigned tot = s[255];
        __syncthreads();
        carry += tot;
    }
    if (t == 0) bucketBase[NBKT] = carry;   // == N_EDGES
}

// ---------- scat1: scatter edges into bucket-grouped records (LDS cursors) ----------
// rec = { (row<<8)|col_local , ea_bits }
__global__ void k_scat1(const int* __restrict__ row, const int* __restrict__ col,
                        const float* __restrict__ ea,
                        const unsigned* __restrict__ histG,
                        const unsigned* __restrict__ bucketBase,
                        int2* __restrict__ recs) {
    __shared__ unsigned base_l[NBKT];
    __shared__ unsigned cursor[NBKT];
    int blk = blockIdx.x, t = threadIdx.x;
    for (int i = t; i < NBKT; i += 256) {
        base_l[i] = bucketBase[i] + histG[(size_t)i * NCHK + blk];
        cursor[i] = 0;
    }
    __syncthreads();
    int e0 = blk * 1024 + t;
#pragma unroll
    for (int k = 0; k < 4; k++) {
        int e = e0 + k * 256;
        if (e < N_EDGES) {
            int c = col[e];
            int bkt = c >> 8;
            unsigned r = atomicAdd(&cursor[bkt], 1u);
            int pos = (int)(base_l[bkt] + r);
            recs[pos] = make_int2((row[e] << 8) | (c & 255), __float_as_int(ea[e]));
        }
    }
}

// ---------- pass2a: per-bucket node count + Q16 wsum -> start/cnt/dinv ----------
__global__ void k_pass2a(const int2* __restrict__ recs,
                         const unsigned* __restrict__ bucketBase,
                         int* __restrict__ start, int* __restrict__ cnt,
                         float* __restrict__ dinv) {
    __shared__ unsigned cntL[256];
    __shared__ unsigned wsL[256];
    __shared__ unsigned s[256];
    int B = blockIdx.x, t = threadIdx.x;
    cntL[t] = 0; wsL[t] = 0;
    __syncthreads();
    int lo = (int)bucketBase[B], hi = (int)bucketBase[B + 1];
    for (int i = lo + t; i < hi; i += 256) {
        int2 rc = recs[i];
        int cl = rc.x & 255;
        atomicAdd(&cntL[cl], 1u);
        unsigned q = __float2uint_rn(__int_as_float(rc.y) * 65536.0f);
        atomicAdd(&wsL[cl], q);
    }
    __syncthreads();
    unsigned v = cntL[t];
    s[t] = v; __syncthreads();
    for (int off = 1; off < 256; off <<= 1) {
        unsigned u = (t >= off) ? s[t - off] : 0;
        __syncthreads();
        s[t] += u;
        __syncthreads();
    }
    int node = B * 256 + t;
    if (node < N_NODES) {
        start[node] = (int)(bucketBase[B] + s[t] - v);
        cnt[node] = (int)v;
        dinv[node] = rsqrtf((float)(65536u + wsL[t]) * (1.0f / 65536.0f));
    }
}

// ---------- pass2b: final CSR slots (LDS cursors), w = ea * dinv[row] ----------
__global__ void k_pass2b(const int2* __restrict__ recs,
                         const unsigned* __restrict__ bucketBase,
                         const int* __restrict__ start,
                         const float* __restrict__ dinv,
                         int2* __restrict__ csr) {
    __shared__ int startL[256];
    __shared__ unsigned cur[256];
    int B = blockIdx.x, t = threadIdx.x;
    int node = B * 256 + t;
    startL[t] = (node < N_NODES) ? start[node] : 0;
    cur[t] = 0;
    __syncthreads();
    int lo = (int)bucketBase[B], hi = (int)bucketBase[B + 1];
    for (int i = lo + t; i < hi; i += 256) {
        int2 rc = recs[i];
        int cl = rc.x & 255;
        int rw = rc.x >> 8;
        float w = __int_as_float(rc.y) * dinv[rw];
        unsigned r = atomicAdd(&cur[cl], 1u);
        csr[startL[cl] + (int)r] = make_int2(rw, __float_as_int(w));
    }
}

// ---------- aggregation layer 1: wave/node, predicated 20-slot gather ----------
// h1[c] = relu(di*(di*h[c] + sum w_e*h[row_e]) + b1),  w_e = ea*dinv[row]
__global__ void k_agg1(const unsigned short* __restrict__ h, const int2* __restrict__ csr,
                       const int* __restrict__ start, const int* __restrict__ cnt,
                       const float* __restrict__ dinv, const float* __restrict__ b1,
                       unsigned short* __restrict__ h1) {
    int c = (blockIdx.x * blockDim.x + threadIdx.x) >> 6;
    int lane = threadIdx.x & 63;
    if (c >= N_NODES) return;
    int eg = lane >> 4, cl = lane & 15;
    float di = dinv[c];
    int s = start[c];
    int n = cnt[c];

    float w[5]; int r[5];
#pragma unroll
    for (int t = 0; t < 5; t++) {
        int i = eg + 4 * t;
        int2 p = csr[s + ((i < n) ? i : 0)];
        bool val = (i < n);
        r[t] = val ? p.x : c;
        w[t] = val ? __int_as_float(p.y) : 0.f;
    }
    uint4 gv[5];
#pragma unroll
    for (int t = 0; t < 5; t++)
        gv[t] = *(const uint4*)(h + (long)r[t] * H_DIM + cl * 8);
    uint4 selfv = (eg == 0) ? *(const uint4*)(h + (long)c * H_DIM + cl * 8)
                            : (uint4){0, 0, 0, 0};

    f32x2 acc[4];
#pragma unroll
    for (int k = 0; k < 4; k++) acc[k] = (f32x2){0.f, 0.f};
    {
        unsigned sv[4] = {selfv.x, selfv.y, selfv.z, selfv.w};
        f32x2 dd = (f32x2){di, di};
        if (eg == 0)
#pragma unroll
            for (int k = 0; k < 4; k++) acc[k] += dd * bfpair(sv[k]);
    }
#pragma unroll
    for (int t = 0; t < 5; t++) {
        unsigned vv[4] = {gv[t].x, gv[t].y, gv[t].z, gv[t].w};
        f32x2 ww = (f32x2){w[t], w[t]};
#pragma unroll
        for (int k = 0; k < 4; k++) acc[k] += ww * bfpair(vv[k]);
    }
    for (int i = 20 + eg; i < n; i += 4) {
        int2 p = csr[s + i];
        uint4 v4 = *(const uint4*)(h + (long)p.x * H_DIM + cl * 8);
        unsigned vv[4] = {v4.x, v4.y, v4.z, v4.w};
        float wt = __int_as_float(p.y);
        f32x2 ww = (f32x2){wt, wt};
#pragma unroll
        for (int k = 0; k < 4; k++) acc[k] += ww * bfpair(vv[k]);
    }
#pragma unroll
    for (int k = 0; k < 4; k++) {
        acc[k].x += __shfl_xor(acc[k].x, 16); acc[k].y += __shfl_xor(acc[k].y, 16);
        acc[k].x += __shfl_xor(acc[k].x, 32); acc[k].y += __shfl_xor(acc[k].y, 32);
    }
    if (eg == 0) {
        u16x8 o;
#pragma unroll
        for (int k = 0; k < 4; k++) {
            o[2 * k]     = f2bf(fmaxf(di * acc[k].x + b1[cl * 8 + 2 * k], 0.f));
            o[2 * k + 1] = f2bf(fmaxf(di * acc[k].y + b1[cl * 8 + 2 * k + 1], 0.f));
        }
        *(u16x8*)(h1 + (long)c * H_DIM + cl * 8) = o;
    }
}

// ---------- GEMM2: h2(bf16) = h1 @ W2 (unscaled), LDS store-transpose ----------
__global__ __launch_bounds__(256, 4) void k_gemm2(const unsigned short* __restrict__ h1,
                        const unsigned short* __restrict__ Wp,
                        unsigned short* __restrict__ h2) {
    __shared__ unsigned short lds_out[64 * C_DIM];
    int tid = threadIdx.x;
    int wave = tid >> 6, lane = tid & 63;
    int m = lane & 15, q = lane >> 4;
    int row0 = blockIdx.x * 64 + wave * 16;
    int rowA = row0 + m; if (rowA >= N_NODES) rowA = N_NODES - 1;

    f32x4 acc[3];
#pragma unroll
    for (int i = 0; i < 3; i++) acc[i] = (f32x4){0.f, 0.f, 0.f, 0.f};
    const unsigned short* hr = h1 + (long)rowA * H_DIM + q * 8;
#pragma unroll
    for (int ks = 0; ks < 4; ks++) {
        bf8 a = *(const bf8*)(hr + ks * 32);
#pragma unroll
        for (int nt = 0; nt < 3; nt++) {
            bf8 b = *(const bf8*)(Wp + (((nt * 4 + ks) * 64 + lane) << 3));
            acc[nt] = __builtin_amdgcn_mfma_f32_16x16x32_bf16(a, b, acc[nt], 0, 0, 0);
        }
    }
    int lrow = wave * 16 + q * 4;
#pragma unroll
    for (int nt = 0; nt < 3; nt++)
#pragma unroll
        for (int r = 0; r < 4; r++) {
            int colo = nt * 16 + m;
            if (colo < C_DIM)
                lds_out[(lrow + r) * C_DIM + colo] = f2bf(acc[nt][r]);
        }
    __syncthreads();
    int valid = N_NODES - blockIdx.x * 64; if (valid > 64) valid = 64;
    unsigned short* gbase = h2 + (size_t)blockIdx.x * 64 * C_DIM;
    int total = valid * C_DIM;
#pragma unroll
    for (int i = 0; i < 3; i++) {
        int idx = (i * 256 + tid) * 4;
        if (idx < total)
            *(uint2*)(gbase + idx) = *(const uint2*)(lds_out + idx);
    }
}

// ---------- aggregation layer 2 + bias + log_softmax: predicated 24-slot gather ----------
__global__ void k_agg2(const unsigned short* __restrict__ h2, const int2* __restrict__ csr,
                       const int* __restrict__ start, const int* __restrict__ cnt,
                       const float* __restrict__ dinv, const float* __restrict__ b2,
                       float* __restrict__ out) {
    int c = (blockIdx.x * blockDim.x + threadIdx.x) >> 6;
    int lane = threadIdx.x & 63;
    if (c >= N_NODES) return;
    int eg = lane >> 3, cl = lane & 7;
    float di = dinv[c];
    int s = start[c];
    int n = cnt[c];

    float w[3]; int r[3];
#pragma unroll
    for (int t = 0; t < 3; t++) {
        int i = eg + 8 * t;
        int2 p = csr[s + ((i < n) ? i : 0)];
        bool val = (i < n);
        r[t] = val ? p.x : c;
        w[t] = val ? __int_as_float(p.y) : 0.f;
    }
    uint4 gv[3] = {{0,0,0,0},{0,0,0,0},{0,0,0,0}};
    uint4 selfv = {0, 0, 0, 0};
    if (cl < 5) {
#pragma unroll
        for (int t = 0; t < 3; t++)
            gv[t] = *(const uint4*)(h2 + (long)r[t] * C_DIM + cl * 8);
        if (eg == 0) selfv = *(const uint4*)(h2 + (long)c * C_DIM + cl * 8);
    }
    f32x2 acc[4];
#pragma unroll
    for (int k = 0; k < 4; k++) acc[k] = (f32x2){0.f, 0.f};
    {
        unsigned sv[4] = {selfv.x, selfv.y, selfv.z, selfv.w};
        f32x2 dd = (f32x2){di, di};
        if (eg == 0 && cl < 5)
#pragma unroll
            for (int k = 0; k < 4; k++) acc[k] += dd * bfpair(sv[k]);
    }
#pragma unroll
    for (int t = 0; t < 3; t++) {
        unsigned vv[4] = {gv[t].x, gv[t].y, gv[t].z, gv[t].w};
        f32x2 ww = (f32x2){w[t], w[t]};
#pragma unroll
        for (int k = 0; k < 4; k++) acc[k] += ww * bfpair(vv[k]);
    }
    for (int i = 24 + eg; i < n; i += 8) {
        int2 p = csr[s + i];
        if (cl < 5) {
            uint4 v4 = *(const uint4*)(h2 + (long)p.x * C_DIM + cl * 8);
            unsigned vv[4] = {v4.x, v4.y, v4.z, v4.w};
            float wt = __int_as_float(p.y);
            f32x2 ww = (f32x2){wt, wt};
#pragma unroll
            for (int k = 0; k < 4; k++) acc[k] += ww * bfpair(vv[k]);
        }
    }
#pragma unroll
    for (int k = 0; k < 4; k++) {
        acc[k].x += __shfl_xor(acc[k].x, 8);  acc[k].y += __shfl_xor(acc[k].y, 8);
        acc[k].x += __shfl_xor(acc[k].x, 16); acc[k].y += __shfl_xor(acc[k].y, 16);
        acc[k].x += __shfl_xor(acc[k].x, 32); acc[k].y += __shfl_xor(acc[k].y, 32);
    }
    float v[8];
    float lm = -INFINITY;
    if (cl < 5) {
#pragma unroll
        for (int k = 0; k < 4; k++) {
            v[2 * k]     = di * acc[k].x + b2[cl * 8 + 2 * k];
            v[2 * k + 1] = di * acc[k].y + b2[cl * 8 + 2 * k + 1];
            lm = fmaxf(lm, fmaxf(v[2 * k], v[2 * k + 1]));
        }
    }
    lm = fmaxf(lm, __shfl_xor(lm, 1));
    lm = fmaxf(lm, __shfl_xor(lm, 2));
    lm = fmaxf(lm, __shfl_xor(lm, 4));
    float ls = 0.f;
    if (cl < 5) {
#pragma unroll
        for (int j = 0; j < 8; j++) ls += __expf(v[j] - lm);
    }
    ls += __shfl_xor(ls, 1);
    ls += __shfl_xor(ls, 2);
    ls += __shfl_xor(ls, 4);
    if (eg == 0 && cl < 5) {
        float lsm = lm + logf(ls);
        f32x4 o0, o1;
#pragma unroll
        for (int j = 0; j < 4; j++) { o0[j] = v[j] - lsm; o1[j] = v[j + 4] - lsm; }
        *(f32x4*)(out + (long)c * C_DIM + cl * 8)     = o0;
        *(f32x4*)(out + (long)c * C_DIM + cl * 8 + 4) = o1;
    }
}

extern "C" void kernel_launch(void* const* d_in, const int* in_sizes, int n_in,
                              void* d_out, int out_size, void* d_ws, size_t ws_size,
                              hipStream_t stream) {
    const float* x  = (const float*)d_in[0];
    const int*   ei = (const int*)d_in[1];
    const float* ea = (const float*)d_in[2];
    const float* W1 = (const float*)d_in[3];
    const float* b1 = (const float*)d_in[4];
    const float* W2 = (const float*)d_in[5];
    const float* b2 = (const float*)d_in[6];
    const int* row = ei;
    const int* col = ei + N_EDGES;

    char* ws = (char*)d_ws;
    size_t off = 0;
    auto alloc = [&](size_t bytes) -> void* {
        void* p = ws + off;
        off = (off + bytes + 255) & ~(size_t)255;
        return p;
    };
    unsigned*       histG   = (unsigned*)alloc((size_t)NBKT * NCHK * 4);  // 2.4 MB
    unsigned*       bktTot  = (unsigned*)alloc((size_t)NBKT * 4);
    unsigned*       bktBase = (unsigned*)alloc((size_t)(NBKT + 1) * 4);
    int*            start   = (int*)alloc((size_t)N_NODES * 4);
    int*            cnt     = (int*)alloc((size_t)N_NODES * 4);
    float*          dinv    = (float*)alloc((size_t)N_NODES * 4);
    int2*           recs    = (int2*)alloc((size_t)N_EDGES * 8);
    int2*           csr     = (int2*)alloc((size_t)N_EDGES * 8);   // NOT last: OOB-safe slot reads
    unsigned short* Wp1     = (unsigned short*)alloc(32768 * 2);
    unsigned short* Wp2     = (unsigned short*)alloc(6144 * 2);
    unsigned short* h       = (unsigned short*)alloc((size_t)(N_NODES + 64) * H_DIM * 2);
    unsigned short* h1      = (unsigned short*)alloc((size_t)N_NODES * H_DIM * 2);
    unsigned short* h2      = (unsigned short*)alloc((size_t)(N_NODES + 64) * C_DIM * 2);

    k_pre<<<152, 256, 0, stream>>>(W1, W2, Wp1, Wp2);
    k_mega2<<<NMEGA, 256, 0, stream>>>(x, Wp1, h, col, histG);
    k_scanB<<<NBKT, 256, 0, stream>>>(histG, bktTot);
    k_scanC<<<1, 256, 0, stream>>>(bktTot, bktBase);
    k_scat1<<<NCHK, 256, 0, stream>>>(row, col, ea, histG, bktBase, recs);
    k_pass2a<<<NBKT, 256, 0, stream>>>(recs, bktBase, start, cnt, dinv);
    k_pass2b<<<NBKT, 256, 0, stream>>>(recs, bktBase, start, dinv, csr);
    k_agg1<<<N_NODES / 4, 256, 0, stream>>>(h, csr, start, cnt, dinv, b1, h1);
    k_gemm2<<<(N_NODES + 63) / 64, 256, 0, stream>>>(h1, Wp2, h2);
    k_agg2<<<N_NODES / 4, 256, 0, stream>>>(h2, csr, start, cnt, dinv, b2, (float*)d_out);
}

// Round 4
// 372.138 us; speedup vs baseline: 1.1575x; 1.0971x over previous
//
#include <hip/hip_runtime.h>

#define N_NODES 100000
#define N_EDGES 1600000
#define F_INPUT 256
#define H_DIM   128
#define C_DIM   40
#define NBKT    391                       // node buckets of 256: 391*256 = 100096
#define NCHK    1563                      // 1024-edge chunks: 1563*1024 = 1600512
#define NGEMM1  1563                      // 64-row tiles covering 100032 rows

typedef short  bf8   __attribute__((ext_vector_type(8)));
typedef float  f32x4 __attribute__((ext_vector_type(4)));
typedef float  f32x2 __attribute__((ext_vector_type(2)));
typedef unsigned short u16x8 __attribute__((ext_vector_type(8)));

static __device__ __forceinline__ unsigned short f2bf(float f) {
    union { float f; unsigned u; } v; v.f = f;
    unsigned r = v.u + 0x7FFFu + ((v.u >> 16) & 1u);
    return (unsigned short)(r >> 16);
}
static __device__ __forceinline__ f32x2 bfpair(unsigned u) {
    union { unsigned u; float f; } lo, hi;
    lo.u = u << 16; hi.u = u & 0xFFFF0000u;
    return (f32x2){lo.f, hi.f};
}

// ---------- k_pre: pack W1/W2 into MFMA B-frag layout ----------
__global__ void k_pre(const float* __restrict__ W1, const float* __restrict__ W2,
                      unsigned short* Wp1, unsigned short* Wp2) {
    int idx = blockIdx.x * 256 + threadIdx.x;
    if (idx < 32768) {       // 8 nt * 8 ks * 64 * 8
        int j = idx & 7, lane = (idx >> 3) & 63, ks = (idx >> 9) & 7, nt = idx >> 12;
        int m = lane & 15, q = lane >> 4;
        Wp1[idx] = f2bf(W1[(ks * 32 + q * 8 + j) * H_DIM + nt * 16 + m]);
    }
    int idx2 = idx - 32768;  // 3 nt * 4 ks * 64 * 8 = 6144
    if (idx2 >= 0 && idx2 < 6144) {
        int j = idx2 & 7, lane = (idx2 >> 3) & 63, ks = (idx2 >> 9) & 3, nt = idx2 >> 11;
        int m = lane & 15, q = lane >> 4;
        int n = nt * 16 + m;
        Wp2[idx2] = (n < C_DIM) ? f2bf(W2[(ks * 32 + q * 8 + j) * C_DIM + n]) : (unsigned short)0;
    }
}

// ---------- k_hist: bucket histogram (LDS only, 1.6 KB -> high occupancy) ----------
__global__ void k_hist(const int* __restrict__ col, unsigned* __restrict__ histG) {
    __shared__ unsigned histL[NBKT];
    int chunk = blockIdx.x, tid = threadIdx.x;
    for (int i = tid; i < NBKT; i += 256) histL[i] = 0;
    __syncthreads();
    int e0 = chunk * 1024 + tid;
#pragma unroll
    for (int k = 0; k < 4; k++) {
        int e = e0 + k * 256;
        if (e < N_EDGES) atomicAdd(&histL[col[e] >> 8], 1u);
    }
    __syncthreads();
    for (int i = tid; i < NBKT; i += 256) histG[(size_t)i * NCHK + chunk] = histL[i];
}

// ---------- k_gemm1: h = x@W1 (bf16). Wp staged in LDS; x loads hoisted ----------
// Kills the 64-deep serialized L2 bb-load chain (VGPR=40 pathology).
__global__ __launch_bounds__(256, 2) void k_gemm1(
        const float* __restrict__ x, const unsigned short* __restrict__ Wp,
        unsigned short* __restrict__ h) {
    __shared__ unsigned short sWp[32768];            // 64 KB, whole W1 B-frag
    __shared__ unsigned short lds_out[64 * H_DIM];   // 16 KB output staging
    int tid = threadIdx.x;
    int wave = tid >> 6, lane = tid & 63;
    int m = lane & 15, q = lane >> 4;
    int tile = blockIdx.x;
    int row0 = tile * 64 + wave * 16;
    int rowA = row0 + m; if (rowA >= N_NODES) rowA = N_NODES - 1;
    const float* xr = x + (long)rowA * F_INPUT + q * 8;

    // issue ALL x loads first: one latency exposure, hidden under Wp staging
    float4 xv[16];
#pragma unroll
    for (int ks = 0; ks < 8; ks++) {
        xv[2 * ks]     = *(const float4*)(xr + ks * 32);
        xv[2 * ks + 1] = *(const float4*)(xr + ks * 32 + 4);
    }
    // cooperative stage of Wp (64 KB): 256 thr x 16 iters x 16 B
#pragma unroll
    for (int it = 0; it < 16; it++) {
        int idx = (it * 256 + tid) * 8;
        *(u16x8*)(sWp + idx) = *(const u16x8*)(Wp + idx);
    }
    __syncthreads();

    f32x4 acc[8];
#pragma unroll
    for (int i = 0; i < 8; i++) acc[i] = (f32x4){0.f, 0.f, 0.f, 0.f};
#pragma unroll
    for (int ks = 0; ks < 8; ks++) {
        float4 a0 = xv[2 * ks], a1 = xv[2 * ks + 1];
        bf8 a;
        a[0] = (short)f2bf(a0.x); a[1] = (short)f2bf(a0.y);
        a[2] = (short)f2bf(a0.z); a[3] = (short)f2bf(a0.w);
        a[4] = (short)f2bf(a1.x); a[5] = (short)f2bf(a1.y);
        a[6] = (short)f2bf(a1.z); a[7] = (short)f2bf(a1.w);
#pragma unroll
        for (int nt = 0; nt < 8; nt++) {
            bf8 bb = *(const bf8*)(sWp + (((nt * 8 + ks) * 64 + lane) << 3));
            acc[nt] = __builtin_amdgcn_mfma_f32_16x16x32_bf16(a, bb, acc[nt], 0, 0, 0);
        }
    }
    int lrow = wave * 16 + q * 4;
#pragma unroll
    for (int nt = 0; nt < 8; nt++)
#pragma unroll
        for (int r = 0; r < 4; r++)
            lds_out[(lrow + r) * H_DIM + nt * 16 + m] = f2bf(acc[nt][r]);
    __syncthreads();
    int valid = N_NODES - tile * 64; if (valid > 64) valid = 64;
    unsigned short* gbase = h + (size_t)tile * 64 * H_DIM;
#pragma unroll
    for (int i = 0; i < 4; i++) {
        int idx = (i * 256 + tid) * 8;
        if (idx < valid * H_DIM)
            *(u16x8*)(gbase + idx) = *(const u16x8*)(lds_out + idx);
    }
}

// ---------- scanB: per-bucket exclusive scan over its 1563 chunk counts ----------
__global__ void k_scanB(unsigned* histG, unsigned* bktTotal) {
    __shared__ unsigned s[256];
    int B = blockIdx.x, t = threadIdx.x;
    unsigned carry = 0;
    for (int c0 = 0; c0 < NCHK; c0 += 256) {
        int idx = c0 + t;
        unsigned v = (idx < NCHK) ? histG[(size_t)B * NCHK + idx] : 0;
        s[t] = v; __syncthreads();
        for (int off = 1; off < 256; off <<= 1) {
            unsigned u = (t >= off) ? s[t - off] : 0;
            __syncthreads();
            s[t] += u;
            __syncthreads();
        }
        if (idx < NCHK) histG[(size_t)B * NCHK + idx] = s[t] - v + carry;
        unsigned tot = s[255];
        __syncthreads();
        carry += tot;
    }
    if (t == 0) bktTotal[B] = carry;
}

// ---------- scanC: exclusive scan of 391 bucket totals -> bucketBase[392] ----------
__global__ void k_scanC(const unsigned* __restrict__ bktTotal, unsigned* bucketBase) {
    __shared__ unsigned s[256];
    int t = threadIdx.x;
    unsigned carry = 0;
    for (int c0 = 0; c0 < NBKT; c0 += 256) {
        int idx = c0 + t;
        unsigned v = (idx < NBKT) ? bktTotal[idx] : 0;
        s[t] = v; __syncthreads();
        for (int off = 1; off < 256; off <<= 1) {
            unsigned u = (t >= off) ? s[t - off] : 0;
            __syncthreads();
            s[t] += u;
            __syncthreads();
        }
        if (idx < NBKT) bucketBase[idx] = s[t] - v + carry;
        unsigned tot = s[255];
        __syncthreads();
        carry += tot;
    }
    if (t == 0) bucketBase[NBKT] = carry;   // == N_EDGES
}

// ---------- scat1: scatter edges into bucket-grouped records (LDS cursors) ----------
// rec = { (row<<8)|col_local , ea_bits }
__global__ void k_scat1(const int* __restrict__ row, const int* __restrict__ col,
                        const float* __restrict__ ea,
                        const unsigned* __restrict__ histG,
                        const unsigned* __restrict__ bucketBase,
                        int2* __restrict__ recs) {
    __shared__ unsigned base_l[NBKT];
    __shared__ unsigned cursor[NBKT];
    int blk = blockIdx.x, t = threadIdx.x;
    for (int i = t; i < NBKT; i += 256) {
        base_l[i] = bucketBase[i] + histG[(size_t)i * NCHK + blk];
        cursor[i] = 0;
    }
    __syncthreads();
    int e0 = blk * 1024 + t;
#pragma unroll
    for (int k = 0; k < 4; k++) {
        int e = e0 + k * 256;
        if (e < N_EDGES) {
            int c = col[e];
            int bkt = c >> 8;
            unsigned r = atomicAdd(&cursor[bkt], 1u);
            int pos = (int)(base_l[bkt] + r);
            recs[pos] = make_int2((row[e] << 8) | (c & 255), __float_as_int(ea[e]));
        }
    }
}

// ---------- pass2a: per-bucket node count + Q16 wsum -> start/cnt/dinv ----------
__global__ void k_pass2a(const int2* __restrict__ recs,
                         const unsigned* __restrict__ bucketBase,
                         int* __restrict__ start, int* __restrict__ cnt,
                         float* __restrict__ dinv) {
    __shared__ unsigned cntL[256];
    __shared__ unsigned wsL[256];
    __shared__ unsigned s[256];
    int B = blockIdx.x, t = threadIdx.x;
    cntL[t] = 0; wsL[t] = 0;
    __syncthreads();
    int lo = (int)bucketBase[B], hi = (int)bucketBase[B + 1];
    for (int i = lo + t; i < hi; i += 256) {
        int2 rc = recs[i];
        int cl = rc.x & 255;
        atomicAdd(&cntL[cl], 1u);
        unsigned q = __float2uint_rn(__int_as_float(rc.y) * 65536.0f);
        atomicAdd(&wsL[cl], q);
    }
    __syncthreads();
    unsigned v = cntL[t];
    s[t] = v; __syncthreads();
    for (int off = 1; off < 256; off <<= 1) {
        unsigned u = (t >= off) ? s[t - off] : 0;
        __syncthreads();
        s[t] += u;
        __syncthreads();
    }
    int node = B * 256 + t;
    if (node < N_NODES) {
        start[node] = (int)(bucketBase[B] + s[t] - v);
        cnt[node] = (int)v;
        dinv[node] = rsqrtf((float)(65536u + wsL[t]) * (1.0f / 65536.0f));
    }
}

// ---------- pass2b: final CSR slots (LDS cursors), w = ea * dinv[row] ----------
__global__ void k_pass2b(const int2* __restrict__ recs,
                         const unsigned* __restrict__ bucketBase,
                         const int* __restrict__ start,
                         const float* __restrict__ dinv,
                         int2* __restrict__ csr) {
    __shared__ int startL[256];
    __shared__ unsigned cur[256];
    int B = blockIdx.x, t = threadIdx.x;
    int node = B * 256 + t;
    startL[t] = (node < N_NODES) ? start[node] : 0;
    cur[t] = 0;
    __syncthreads();
    int lo = (int)bucketBase[B], hi = (int)bucketBase[B + 1];
    for (int i = lo + t; i < hi; i += 256) {
        int2 rc = recs[i];
        int cl = rc.x & 255;
        int rw = rc.x >> 8;
        float w = __int_as_float(rc.y) * dinv[rw];
        unsigned r = atomicAdd(&cur[cl], 1u);
        csr[startL[cl] + (int)r] = make_int2(rw, __float_as_int(w));
    }
}

// ---------- aggregation layer 1: wave/node, predicated 20-slot gather ----------
// h1[c] = relu(di*(di*h[c] + sum w_e*h[row_e]) + b1),  w_e = ea*dinv[row]
__global__ void k_agg1(const unsigned short* __restrict__ h, const int2* __restrict__ csr,
                       const int* __restrict__ start, const int* __restrict__ cnt,
                       const float* __restrict__ dinv, const float* __restrict__ b1,
                       unsigned short* __restrict__ h1) {
    int c = (blockIdx.x * blockDim.x + threadIdx.x) >> 6;
    int lane = threadIdx.x & 63;
    if (c >= N_NODES) return;
    int eg = lane >> 4, cl = lane & 15;
    float di = dinv[c];
    int s = start[c];
    int n = cnt[c];

    float w[5]; int r[5];
#pragma unroll
    for (int t = 0; t < 5; t++) {
        int i = eg + 4 * t;
        int2 p = csr[s + ((i < n) ? i : 0)];
        bool val = (i < n);
        r[t] = val ? p.x : c;
        w[t] = val ? __int_as_float(p.y) : 0.f;
    }
    uint4 gv[5];
#pragma unroll
    for (int t = 0; t < 5; t++)
        gv[t] = *(const uint4*)(h + (long)r[t] * H_DIM + cl * 8);
    uint4 selfv = (eg == 0) ? *(const uint4*)(h + (long)c * H_DIM + cl * 8)
                            : (uint4){0, 0, 0, 0};

    f32x2 acc[4];
#pragma unroll
    for (int k = 0; k < 4; k++) acc[k] = (f32x2){0.f, 0.f};
    {
        unsigned sv[4] = {selfv.x, selfv.y, selfv.z, selfv.w};
        f32x2 dd = (f32x2){di, di};
        if (eg == 0)
#pragma unroll
            for (int k = 0; k < 4; k++) acc[k] += dd * bfpair(sv[k]);
    }
#pragma unroll
    for (int t = 0; t < 5; t++) {
        unsigned vv[4] = {gv[t].x, gv[t].y, gv[t].z, gv[t].w};
        f32x2 ww = (f32x2){w[t], w[t]};
#pragma unroll
        for (int k = 0; k < 4; k++) acc[k] += ww * bfpair(vv[k]);
    }
    for (int i = 20 + eg; i < n; i += 4) {
        int2 p = csr[s + i];
        uint4 v4 = *(const uint4*)(h + (long)p.x * H_DIM + cl * 8);
        unsigned vv[4] = {v4.x, v4.y, v4.z, v4.w};
        float wt = __int_as_float(p.y);
        f32x2 ww = (f32x2){wt, wt};
#pragma unroll
        for (int k = 0; k < 4; k++) acc[k] += ww * bfpair(vv[k]);
    }
#pragma unroll
    for (int k = 0; k < 4; k++) {
        acc[k].x += __shfl_xor(acc[k].x, 16); acc[k].y += __shfl_xor(acc[k].y, 16);
        acc[k].x += __shfl_xor(acc[k].x, 32); acc[k].y += __shfl_xor(acc[k].y, 32);
    }
    if (eg == 0) {
        u16x8 o;
#pragma unroll
        for (int k = 0; k < 4; k++) {
            o[2 * k]     = f2bf(fmaxf(di * acc[k].x + b1[cl * 8 + 2 * k], 0.f));
            o[2 * k + 1] = f2bf(fmaxf(di * acc[k].y + b1[cl * 8 + 2 * k + 1], 0.f));
        }
        *(u16x8*)(h1 + (long)c * H_DIM + cl * 8) = o;
    }
}

// ---------- GEMM2: h2(bf16) = h1 @ W2 (unscaled), LDS store-transpose ----------
__global__ __launch_bounds__(256, 4) void k_gemm2(const unsigned short* __restrict__ h1,
                        const unsigned short* __restrict__ Wp,
                        unsigned short* __restrict__ h2) {
    __shared__ unsigned short lds_out[64 * C_DIM];
    int tid = threadIdx.x;
    int wave = tid >> 6, lane = tid & 63;
    int m = lane & 15, q = lane >> 4;
    int row0 = blockIdx.x * 64 + wave * 16;
    int rowA = row0 + m; if (rowA >= N_NODES) rowA = N_NODES - 1;

    f32x4 acc[3];
#pragma unroll
    for (int i = 0; i < 3; i++) acc[i] = (f32x4){0.f, 0.f, 0.f, 0.f};
    const unsigned short* hr = h1 + (long)rowA * H_DIM + q * 8;
#pragma unroll
    for (int ks = 0; ks < 4; ks++) {
        bf8 a = *(const bf8*)(hr + ks * 32);
#pragma unroll
        for (int nt = 0; nt < 3; nt++) {
            bf8 b = *(const bf8*)(Wp + (((nt * 4 + ks) * 64 + lane) << 3));
            acc[nt] = __builtin_amdgcn_mfma_f32_16x16x32_bf16(a, b, acc[nt], 0, 0, 0);
        }
    }
    int lrow = wave * 16 + q * 4;
#pragma unroll
    for (int nt = 0; nt < 3; nt++)
#pragma unroll
        for (int r = 0; r < 4; r++) {
            int colo = nt * 16 + m;
            if (colo < C_DIM)
                lds_out[(lrow + r) * C_DIM + colo] = f2bf(acc[nt][r]);
        }
    __syncthreads();
    int valid = N_NODES - blockIdx.x * 64; if (valid > 64) valid = 64;
    unsigned short* gbase = h2 + (size_t)blockIdx.x * 64 * C_DIM;
    int total = valid * C_DIM;
#pragma unroll
    for (int i = 0; i < 3; i++) {
        int idx = (i * 256 + tid) * 4;
        if (idx < total)
            *(uint2*)(gbase + idx) = *(const uint2*)(lds_out + idx);
    }
}

// ---------- aggregation layer 2 + bias + log_softmax: predicated 24-slot gather ----------
__global__ void k_agg2(const unsigned short* __restrict__ h2, const int2* __restrict__ csr,
                       const int* __restrict__ start, const int* __restrict__ cnt,
                       const float* __restrict__ dinv, const float* __restrict__ b2,
                       float* __restrict__ out) {
    int c = (blockIdx.x * blockDim.x + threadIdx.x) >> 6;
    int lane = threadIdx.x & 63;
    if (c >= N_NODES) return;
    int eg = lane >> 3, cl = lane & 7;
    float di = dinv[c];
    int s = start[c];
    int n = cnt[c];

    float w[3]; int r[3];
#pragma unroll
    for (int t = 0; t < 3; t++) {
        int i = eg + 8 * t;
        int2 p = csr[s + ((i < n) ? i : 0)];
        bool val = (i < n);
        r[t] = val ? p.x : c;
        w[t] = val ? __int_as_float(p.y) : 0.f;
    }
    uint4 gv[3] = {{0,0,0,0},{0,0,0,0},{0,0,0,0}};
    uint4 selfv = {0, 0, 0, 0};
    if (cl < 5) {
#pragma unroll
        for (int t = 0; t < 3; t++)
            gv[t] = *(const uint4*)(h2 + (long)r[t] * C_DIM + cl * 8);
        if (eg == 0) selfv = *(const uint4*)(h2 + (long)c * C_DIM + cl * 8);
    }
    f32x2 acc[4];
#pragma unroll
    for (int k = 0; k < 4; k++) acc[k] = (f32x2){0.f, 0.f};
    {
        unsigned sv[4] = {selfv.x, selfv.y, selfv.z, selfv.w};
        f32x2 dd = (f32x2){di, di};
        if (eg == 0 && cl < 5)
#pragma unroll
            for (int k = 0; k < 4; k++) acc[k] += dd * bfpair(sv[k]);
    }
#pragma unroll
    for (int t = 0; t < 3; t++) {
        unsigned vv[4] = {gv[t].x, gv[t].y, gv[t].z, gv[t].w};
        f32x2 ww = (f32x2){w[t], w[t]};
#pragma unroll
        for (int k = 0; k < 4; k++) acc[k] += ww * bfpair(vv[k]);
    }
    for (int i = 24 + eg; i < n; i += 8) {
        int2 p = csr[s + i];
        if (cl < 5) {
            uint4 v4 = *(const uint4*)(h2 + (long)p.x * C_DIM + cl * 8);
            unsigned vv[4] = {v4.x, v4.y, v4.z, v4.w};
            float wt = __int_as_float(p.y);
            f32x2 ww = (f32x2){wt, wt};
#pragma unroll
            for (int k = 0; k < 4; k++) acc[k] += ww * bfpair(vv[k]);
        }
    }
#pragma unroll
    for (int k = 0; k < 4; k++) {
        acc[k].x += __shfl_xor(acc[k].x, 8);  acc[k].y += __shfl_xor(acc[k].y, 8);
        acc[k].x += __shfl_xor(acc[k].x, 16); acc[k].y += __shfl_xor(acc[k].y, 16);
        acc[k].x += __shfl_xor(acc[k].x, 32); acc[k].y += __shfl_xor(acc[k].y, 32);
    }
    float v[8];
    float lm = -INFINITY;
    if (cl < 5) {
#pragma unroll
        for (int k = 0; k < 4; k++) {
            v[2 * k]     = di * acc[k].x + b2[cl * 8 + 2 * k];
            v[2 * k + 1] = di * acc[k].y + b2[cl * 8 + 2 * k + 1];
            lm = fmaxf(lm, fmaxf(v[2 * k], v[2 * k + 1]));
        }
    }
    lm = fmaxf(lm, __shfl_xor(lm, 1));
    lm = fmaxf(lm, __shfl_xor(lm, 2));
    lm = fmaxf(lm, __shfl_xor(lm, 4));
    float ls = 0.f;
    if (cl < 5) {
#pragma unroll
        for (int j = 0; j < 8; j++) ls += __expf(v[j] - lm);
    }
    ls += __shfl_xor(ls, 1);
    ls += __shfl_xor(ls, 2);
    ls += __shfl_xor(ls, 4);
    if (eg == 0 && cl < 5) {
        float lsm = lm + logf(ls);
        f32x4 o0, o1;
#pragma unroll
        for (int j = 0; j < 4; j++) { o0[j] = v[j] - lsm; o1[j] = v[j + 4] - lsm; }
        *(f32x4*)(out + (long)c * C_DIM + cl * 8)     = o0;
        *(f32x4*)(out + (long)c * C_DIM + cl * 8 + 4) = o1;
    }
}

extern "C" void kernel_launch(void* const* d_in, const int* in_sizes, int n_in,
                              void* d_out, int out_size, void* d_ws, size_t ws_size,
                              hipStream_t stream) {
    const float* x  = (const float*)d_in[0];
    const int*   ei = (const int*)d_in[1];
    const float* ea = (const float*)d_in[2];
    const float* W1 = (const float*)d_in[3];
    const float* b1 = (const float*)d_in[4];
    const float* W2 = (const float*)d_in[5];
    const float* b2 = (const float*)d_in[6];
    const int* row = ei;
    const int* col = ei + N_EDGES;

    char* ws = (char*)d_ws;
    size_t off = 0;
    auto alloc = [&](size_t bytes) -> void* {
        void* p = ws + off;
        off = (off + bytes + 255) & ~(size_t)255;
        return p;
    };
    unsigned*       histG   = (unsigned*)alloc((size_t)NBKT * NCHK * 4);  // 2.4 MB
    unsigned*       bktTot  = (unsigned*)alloc((size_t)NBKT * 4);
    unsigned*       bktBase = (unsigned*)alloc((size_t)(NBKT + 1) * 4);
    int*            start   = (int*)alloc((size_t)N_NODES * 4);
    int*            cnt     = (int*)alloc((size_t)N_NODES * 4);
    float*          dinv    = (float*)alloc((size_t)N_NODES * 4);
    int2*           recs    = (int2*)alloc((size_t)N_EDGES * 8);
    int2*           csr     = (int2*)alloc((size_t)N_EDGES * 8);   // NOT last: OOB-safe slot reads
    unsigned short* Wp1     = (unsigned short*)alloc(32768 * 2);
    unsigned short* Wp2     = (unsigned short*)alloc(6144 * 2);
    unsigned short* h       = (unsigned short*)alloc((size_t)(N_NODES + 64) * H_DIM * 2);
    unsigned short* h1      = (unsigned short*)alloc((size_t)N_NODES * H_DIM * 2);
    unsigned short* h2      = (unsigned short*)alloc((size_t)(N_NODES + 64) * C_DIM * 2);

    k_pre<<<152, 256, 0, stream>>>(W1, W2, Wp1, Wp2);
    k_hist<<<NCHK, 256, 0, stream>>>(col, histG);
    k_gemm1<<<NGEMM1, 256, 0, stream>>>(x, Wp1, h);
    k_scanB<<<NBKT, 256, 0, stream>>>(histG, bktTot);
    k_scanC<<<1, 256, 0, stream>>>(bktTot, bktBase);
    k_scat1<<<NCHK, 256, 0, stream>>>(row, col, ea, histG, bktBase, recs);
    k_pass2a<<<NBKT, 256, 0, stream>>>(recs, bktBase, start, cnt, dinv);
    k_pass2b<<<NBKT, 256, 0, stream>>>(recs, bktBase, start, dinv, csr);
    k_agg1<<<N_NODES / 4, 256, 0, stream>>>(h, csr, start, cnt, dinv, b1, h1);
    k_gemm2<<<(N_NODES + 63) / 64, 256, 0, stream>>>(h1, Wp2, h2);
    k_agg2<<<N_NODES / 4, 256, 0, stream>>>(h2, csr, start, cnt, dinv, b2, (float*)d_out);
}